// Round 2
// baseline (502.762 us; speedup 1.0000x reference)
//
#include <hip/hip_runtime.h>

// Problem constants (fixed by the reference)
#define NN 50000      // num_nodes
#define NR 16         // num_relations
#define NB 4          // num_bases
#define DD 128        // dim
#define CAP 96        // per-node edge bucket capacity (max degree ~58 for Poisson(32))

// Workspace layout (bytes):
//   [0, NN*4)                  : cnt   (per-target edge counts)
//   [1 MB, 1 MB + NN*CAP*8)    : rec   (packed edge records, int2) = 38.4 MB
//   [40 MB, 40 MB + NN*512*4)  : g     (N, B*D) fp32               = 102.4 MB
static const size_t OFF_REC = (size_t)1 << 20;
static const size_t OFF_G   = (size_t)40 << 20;

__global__ void fill_kernel(const int* __restrict__ src, const int* __restrict__ tgt,
                            const int* __restrict__ et, const float* __restrict__ ew,
                            int* __restrict__ cnt, int2* __restrict__ rec, int E) {
    int e = blockIdx.x * blockDim.x + threadIdx.x;
    if (e >= E) return;
    int t = tgt[e];
    int pos = atomicAdd(&cnt[t], 1);
    if (pos < CAP) {
        int2 r;
        r.x = src[e] | (et[e] << 16);   // src < 65536, et < 16
        r.y = __float_as_int(ew[e]);
        rec[t * CAP + pos] = r;
    }
}

// One wave (64 lanes) per target node. Lane l owns columns {2l, 2l+1} of each
// of the 4 base-accumulators (8 floats in registers). x rows are gathered
// (LLC-resident, 25.6 MB); g written without atomics.
__global__ __launch_bounds__(256) void agg_kernel(const float* __restrict__ x,
                                                  const float* __restrict__ bw, // (R, B)
                                                  const int* __restrict__ cnt,
                                                  const int2* __restrict__ rec,
                                                  float* __restrict__ g) {
    __shared__ float sbw[NR * NB];
    int tid = threadIdx.x;
    if (tid < NR * NB) sbw[tid] = bw[tid];
    __syncthreads();

    int wave = tid >> 6;
    int lane = tid & 63;
    int n = blockIdx.x * 4 + wave;   // grid sized so n < NN always

    int deg = cnt[n];
    if (deg > CAP) deg = CAP;

    float2 acc[NB];
#pragma unroll
    for (int b = 0; b < NB; ++b) acc[b] = make_float2(0.f, 0.f);

    const int2* r = rec + (size_t)n * CAP;
    for (int j = 0; j < deg; ++j) {
        int2 rc = r[j];                       // wave-uniform broadcast load
        int s = rc.x & 0xFFFF;
        int e = rc.x >> 16;
        float w = __int_as_float(rc.y);
        float2 xv = *(const float2*)&x[(size_t)s * DD + lane * 2];
#pragma unroll
        for (int b = 0; b < NB; ++b) {
            float c = w * sbw[e * NB + b];
            acc[b].x += c * xv.x;
            acc[b].y += c * xv.y;
        }
    }

    float* go = g + (size_t)n * (NB * DD);
#pragma unroll
    for (int b = 0; b < NB; ++b) {
        *(float2*)&go[b * DD + lane * 2] = acc[b];
    }
}

// out (N,128) = g (N,512) @ W (512,128), W = bases viewed flat (b*128+i, o).
// Block: 256 threads, tile 32 rows x 128 cols, K staged in LDS 64 at a time.
// Thread (rg = tid>>5, oq = tid&31) computes rows rg*4..rg*4+3, cols oq*4..+3.
#define KT 64
#define BM 32
__global__ __launch_bounds__(256) void gemm_kernel(const float* __restrict__ g,
                                                   const float* __restrict__ W,
                                                   float* __restrict__ out) {
    __shared__ float wt[KT][DD];   // 32 KB
    __shared__ float gt[BM][KT];   // 8 KB
    int tid = threadIdx.x;
    int row0 = blockIdx.x * BM;
    int oq = tid & 31;
    int rg = tid >> 5;

    float4 acc[4];
#pragma unroll
    for (int i = 0; i < 4; ++i) acc[i] = make_float4(0.f, 0.f, 0.f, 0.f);

    for (int kt = 0; kt < 512 / KT; ++kt) {
        // stage W tile: 64x128 floats = 2048 float4 slots
#pragma unroll
        for (int j = 0; j < 8; ++j) {
            int slot = tid + j * 256;
            int rr = slot >> 5, q = slot & 31;
            *(float4*)&wt[rr][q * 4] = *(const float4*)&W[(size_t)(kt * KT + rr) * DD + q * 4];
        }
        // stage g tile: 32x64 floats = 512 float4 slots
#pragma unroll
        for (int j = 0; j < 2; ++j) {
            int slot = tid + j * 256;
            int rr = slot >> 4, q = slot & 15;
            int grow = row0 + rr;
            float4 v = make_float4(0.f, 0.f, 0.f, 0.f);
            if (grow < NN) v = *(const float4*)&g[(size_t)grow * 512 + kt * KT + q * 4];
            *(float4*)&gt[rr][q * 4] = v;
        }
        __syncthreads();

#pragma unroll
        for (int k4 = 0; k4 < KT / 4; ++k4) {
            float4 w0 = *(float4*)&wt[k4 * 4 + 0][oq * 4];
            float4 w1 = *(float4*)&wt[k4 * 4 + 1][oq * 4];
            float4 w2 = *(float4*)&wt[k4 * 4 + 2][oq * 4];
            float4 w3 = *(float4*)&wt[k4 * 4 + 3][oq * 4];
#pragma unroll
            for (int rr = 0; rr < 4; ++rr) {
                float4 gv = *(float4*)&gt[rg * 4 + rr][k4 * 4];
                acc[rr].x += gv.x * w0.x + gv.y * w1.x + gv.z * w2.x + gv.w * w3.x;
                acc[rr].y += gv.x * w0.y + gv.y * w1.y + gv.z * w2.y + gv.w * w3.y;
                acc[rr].z += gv.x * w0.z + gv.y * w1.z + gv.z * w2.z + gv.w * w3.z;
                acc[rr].w += gv.x * w0.w + gv.y * w1.w + gv.z * w2.w + gv.w * w3.w;
            }
        }
        __syncthreads();
    }

#pragma unroll
    for (int rr = 0; rr < 4; ++rr) {
        int grow = row0 + rg * 4 + rr;
        if (grow < NN) *(float4*)&out[(size_t)grow * DD + oq * 4] = acc[rr];
    }
}

extern "C" void kernel_launch(void* const* d_in, const int* in_sizes, int n_in,
                              void* d_out, int out_size, void* d_ws, size_t ws_size,
                              hipStream_t stream) {
    const float* x   = (const float*)d_in[0];
    const int* src   = (const int*)d_in[1];
    const int* tgt   = (const int*)d_in[2];
    const int* et    = (const int*)d_in[3];
    const float* ew  = (const float*)d_in[4];
    const float* bw  = (const float*)d_in[5];   // (R, B)
    const float* bas = (const float*)d_in[6];   // (B, D, D) == (512, 128) flat
    float* out = (float*)d_out;

    int E = in_sizes[1];

    char* ws = (char*)d_ws;
    int*  cnt = (int*)ws;
    int2* rec = (int2*)(ws + OFF_REC);
    float* g  = (float*)(ws + OFF_G);

    hipMemsetAsync(cnt, 0, NN * sizeof(int), stream);

    fill_kernel<<<(E + 255) / 256, 256, 0, stream>>>(src, tgt, et, ew, cnt, rec, E);

    agg_kernel<<<NN / 4, 256, 0, stream>>>(x, bw, cnt, rec, g);

    gemm_kernel<<<(NN + BM - 1) / BM, 256, 0, stream>>>(g, bas, out);
}

// Round 4
// 331.939 us; speedup vs baseline: 1.5146x; 1.5146x over previous
//
#include <hip/hip_runtime.h>

// Problem constants (fixed by the reference)
#define NN 50000      // num_nodes
#define NR 16         // num_relations
#define NB 4          // num_bases
#define DD 128        // dim
#define CAP 96        // per-node edge bucket capacity (max degree ~58 for Poisson(32))

typedef __attribute__((ext_vector_type(8))) short bf16x8;
typedef __attribute__((ext_vector_type(4))) float f32x4;

// Workspace layout (bytes):
//   [0, NN*4)                   : cnt    (per-target edge counts)         0.2 MB
//   [1 MB, +NN*CAP*8)           : rec    (packed edge records, int2)      38.4 MB
//   [40 MB, +NN*512*2)          : g_bf16 (N, B*D) bf16                    51.2 MB
//   [96 MB, +512*128*2)         : Wf     (frag-ordered bases, bf16)       0.13 MB
static const size_t OFF_REC = (size_t)1 << 20;
static const size_t OFF_G   = (size_t)40 << 20;
static const size_t OFF_WF  = (size_t)96 << 20;

static __device__ __forceinline__ unsigned short f2bf(float f) {
    unsigned int u = __float_as_uint(f);
    unsigned int r = (u + 0x7FFF + ((u >> 16) & 1)) >> 16;   // RNE
    return (unsigned short)r;
}

__global__ void fill_kernel(const int* __restrict__ src, const int* __restrict__ tgt,
                            const int* __restrict__ et, const float* __restrict__ ew,
                            int* __restrict__ cnt, int2* __restrict__ rec, int E) {
    int e = blockIdx.x * blockDim.x + threadIdx.x;
    if (e >= E) return;
    int t = tgt[e];
    int pos = atomicAdd(&cnt[t], 1);
    if (pos < CAP) {
        int2 r;
        r.x = src[e] | (et[e] << 16);   // src < 65536, et < 16
        r.y = __float_as_int(ew[e]);
        rec[t * CAP + pos] = r;
    }
}

// Reorder bases (512,128) fp32 -> bf16 B-fragment order for 16x16x32 MFMA.
// Frag (ks, nt): lane l holds B[k = ks*32 + (l>>4)*8 + j][col = nt*16 + (l&15)], j=0..7.
// Stored at Wf[((ks*8 + nt)*64 + l)*8 + j]  (16B per lane, coalesced reads).
__global__ void prep_kernel(const float* __restrict__ W, unsigned short* __restrict__ Wf) {
    int t = blockIdx.x * 256 + threadIdx.x;   // 0..8191
    int lane = t & 63;
    int ft = t >> 6;          // ks*8 + nt
    int ks = ft >> 3, nt = ft & 7;
    int col = nt * 16 + (lane & 15);
    int k0 = ks * 32 + (lane >> 4) * 8;
    union { unsigned short v[8]; uint4 u; } pk;
#pragma unroll
    for (int j = 0; j < 8; ++j) pk.v[j] = f2bf(W[(size_t)(k0 + j) * DD + col]);
    ((uint4*)Wf)[t] = pk.u;
}

// One wave per target node; lane l owns cols {2l,2l+1} of the 4 base-accumulators.
// Edge loop unrolled x4: batch record loads (2x int4) + 4 independent x-row
// gathers issued before the FMA block to break the latency chain.
__global__ __launch_bounds__(256) void agg_kernel(const float* __restrict__ x,
                                                  const float* __restrict__ bw, // (R, B)
                                                  const int* __restrict__ cnt,
                                                  const int2* __restrict__ rec,
                                                  unsigned int* __restrict__ g) { // bf16x2 words
    __shared__ float sbw[NR * NB];
    int tid = threadIdx.x;
    if (tid < NR * NB) sbw[tid] = bw[tid];
    __syncthreads();

    int wave = tid >> 6;
    int lane = tid & 63;
    int n = blockIdx.x * 4 + wave;   // grid sized so n < NN always

    int deg = cnt[n];
    if (deg > CAP) deg = CAP;

    float2 acc[NB];
#pragma unroll
    for (int b = 0; b < NB; ++b) acc[b] = make_float2(0.f, 0.f);

    const int2* r = rec + (size_t)n * CAP;
    int j = 0;
    for (; j + 4 <= deg; j += 4) {
        int4 ra = *(const int4*)&r[j];       // records j, j+1
        int4 rb = *(const int4*)&r[j + 2];   // records j+2, j+3
        float2 xv0 = *(const float2*)&x[(size_t)(ra.x & 0xFFFF) * DD + lane * 2];
        float2 xv1 = *(const float2*)&x[(size_t)(ra.z & 0xFFFF) * DD + lane * 2];
        float2 xv2 = *(const float2*)&x[(size_t)(rb.x & 0xFFFF) * DD + lane * 2];
        float2 xv3 = *(const float2*)&x[(size_t)(rb.z & 0xFFFF) * DD + lane * 2];
        float w0 = __int_as_float(ra.y); int e0 = ra.x >> 16;
        float w1 = __int_as_float(ra.w); int e1 = ra.z >> 16;
        float w2 = __int_as_float(rb.y); int e2 = rb.x >> 16;
        float w3 = __int_as_float(rb.w); int e3 = rb.z >> 16;
#pragma unroll
        for (int b = 0; b < NB; ++b) {
            float c0 = w0 * sbw[e0 * NB + b];
            float c1 = w1 * sbw[e1 * NB + b];
            float c2 = w2 * sbw[e2 * NB + b];
            float c3 = w3 * sbw[e3 * NB + b];
            acc[b].x += c0 * xv0.x + c1 * xv1.x + c2 * xv2.x + c3 * xv3.x;
            acc[b].y += c0 * xv0.y + c1 * xv1.y + c2 * xv2.y + c3 * xv3.y;
        }
    }
    for (; j < deg; ++j) {
        int2 rc = r[j];
        int s = rc.x & 0xFFFF;
        int e = rc.x >> 16;
        float w = __int_as_float(rc.y);
        float2 xv = *(const float2*)&x[(size_t)s * DD + lane * 2];
#pragma unroll
        for (int b = 0; b < NB; ++b) {
            float c = w * sbw[e * NB + b];
            acc[b].x += c * xv.x;
            acc[b].y += c * xv.y;
        }
    }

    // store g row as bf16: word index n*256 + b*64 + lane  (cols 2l,2l+1)
    unsigned int* go = g + (size_t)n * (NB * DD / 2);
#pragma unroll
    for (int b = 0; b < NB; ++b) {
        unsigned int w = (unsigned int)f2bf(acc[b].x) | ((unsigned int)f2bf(acc[b].y) << 16);
        go[b * 64 + lane] = w;
    }
}

// out (N,128) = g_bf16 (N,512) @ Wf (frag-ordered 512x128 bf16), via MFMA.
// One wave per 16-row tile; 8 col-tiles x 16 K-steps; no LDS, no barriers.
__global__ __launch_bounds__(256) void gemm_mfma(const unsigned short* __restrict__ g,
                                                 const unsigned short* __restrict__ Wf,
                                                 float* __restrict__ out) {
    int tid = threadIdx.x;
    int wid = tid >> 6;
    int lane = tid & 63;
    int rt = blockIdx.x * 4 + wid;          // row tile (16 rows)
    if (rt >= (NN + 15) / 16) return;
    int row0 = rt * 16;

    const bf16x8* ga = (const bf16x8*)(g + (size_t)(row0 + (lane & 15)) * 512);
    const bf16x8* wb = (const bf16x8*)Wf;
    int kgrp = lane >> 4;

    f32x4 acc[8];
#pragma unroll
    for (int nt = 0; nt < 8; ++nt) acc[nt] = (f32x4){0.f, 0.f, 0.f, 0.f};

#pragma unroll
    for (int ks = 0; ks < 16; ++ks) {
        bf16x8 a = ga[ks * 4 + kgrp];
#pragma unroll
        for (int nt = 0; nt < 8; ++nt) {
            bf16x8 b = wb[(ks * 8 + nt) * 64 + lane];
            acc[nt] = __builtin_amdgcn_mfma_f32_16x16x32_bf16(a, b, acc[nt], 0, 0, 0);
        }
    }

    // D layout: col = lane&15, row = (lane>>4)*4 + reg
    int col = lane & 15;
#pragma unroll
    for (int nt = 0; nt < 8; ++nt) {
#pragma unroll
        for (int q = 0; q < 4; ++q) {
            int row = row0 + kgrp * 4 + q;
            out[(size_t)row * DD + nt * 16 + col] = acc[nt][q];
        }
    }
}

extern "C" void kernel_launch(void* const* d_in, const int* in_sizes, int n_in,
                              void* d_out, int out_size, void* d_ws, size_t ws_size,
                              hipStream_t stream) {
    const float* x   = (const float*)d_in[0];
    const int* src   = (const int*)d_in[1];
    const int* tgt   = (const int*)d_in[2];
    const int* et    = (const int*)d_in[3];
    const float* ew  = (const float*)d_in[4];
    const float* bw  = (const float*)d_in[5];   // (R, B)
    const float* bas = (const float*)d_in[6];   // (B, D, D) == (512, 128) flat
    float* out = (float*)d_out;

    int E = in_sizes[1];

    char* ws = (char*)d_ws;
    int*  cnt = (int*)ws;
    int2* rec = (int2*)(ws + OFF_REC);
    unsigned int*   gw = (unsigned int*)(ws + OFF_G);
    unsigned short* gs = (unsigned short*)(ws + OFF_G);
    unsigned short* Wf = (unsigned short*)(ws + OFF_WF);

    hipMemsetAsync(cnt, 0, NN * sizeof(int), stream);

    fill_kernel<<<(E + 255) / 256, 256, 0, stream>>>(src, tgt, et, ew, cnt, rec, E);
    prep_kernel<<<32, 256, 0, stream>>>(bas, Wf);

    agg_kernel<<<NN / 4, 256, 0, stream>>>(x, bw, cnt, rec, gw);

    gemm_mfma<<<(NN / 16 + 3) / 4, 256, 0, stream>>>(gs, Wf, out);
}